// Round 13
// baseline (137.593 us; speedup 1.0000x reference)
//
#include <hip/hip_runtime.h>
#include <math.h>
#include <stdint.h>

#define B_   4
#define C_   256
#define T_   8
#define HW_  1024
#define PM_  8192
#define PR_  1024
#define NM_  (C_ * PM_)
#define NR_  (C_ * PR_)
#define NBM  128
#define NBR  16
#define EPS_ 1e-6f
// c^-0.5 * log2(e): fold softmax base-2 conversion into Q so attn uses exp2
#define QSCALE 0.09016844f

typedef unsigned short u16;
typedef unsigned int u32;
typedef __attribute__((ext_vector_type(8))) short short8;   // 8 bf16 = 4 VGPR
typedef __attribute__((ext_vector_type(4))) float f32x4;
typedef __attribute__((ext_vector_type(16))) float f32x16;

__device__ inline u16 f2bf(float f) {                 // RNE f32->bf16
    uint32_t u = __builtin_bit_cast(uint32_t, f);
    u += 0x7fffu + ((u >> 16) & 1u);
    return (u16)(u >> 16);
}
__device__ inline u32 pk2bf(float a, float b) {
    return (u32)f2bf(a) | ((u32)f2bf(b) << 16);
}

__device__ inline f32x4 mfma16(short8 a, short8 b, f32x4 c) {
    f32x4 d;
    asm("v_mfma_f32_16x16x32_bf16 %0, %1, %2, %3" : "=v"(d) : "v"(a), "v"(b), "0"(c));
    return d;
}
__device__ inline f32x16 mfma32(short8 a, short8 b, f32x16 c) {
    f32x16 d;
    asm("v_mfma_f32_32x32x16_bf16 %0, %1, %2, %3" : "=v"(d) : "v"(a), "v"(b), "0"(c));
    return d;
}
__device__ __forceinline__ short8 lds8(const char* p) {
    return __builtin_bit_cast(short8, *(const uint4*)p);
}
// async global->LDS, 16B/lane; dest = wave-uniform base + lane*16 (linear).
__device__ __forceinline__ void gl16(const void* g, void* l) {
    __builtin_amdgcn_global_load_lds(
        reinterpret_cast<const uint32_t __attribute__((address_space(1)))*>(
            reinterpret_cast<uintptr_t>(g)),
        reinterpret_cast<uint32_t __attribute__((address_space(3)))*>(
            reinterpret_cast<uintptr_t>(l)),
        16, 0, 0);
}

// ---------------------------------------------------------------------------
// Kernel 1 (merged): GroupNorm partial sums for motion (blocks 0..511) and
// ref (blocks 512..575), deterministic two-stage.
// ---------------------------------------------------------------------------
__device__ void gn_body(const float* __restrict__ x, int per_sample, int nblk,
                        float* __restrict__ part, int bid) {
    int b   = bid / nblk;
    int blk = bid % nblk;
    const float* xb = x + (size_t)b * per_sample;
    int chunk = per_sample / nblk;
    int base  = blk * chunk;
    float s = 0.f, s2 = 0.f;
    for (int i = threadIdx.x * 4; i < chunk; i += 256 * 4) {
        float4 v = *(const float4*)(xb + base + i);
        s  += v.x + v.y + v.z + v.w;
        s2 += v.x * v.x + v.y * v.y + v.z * v.z + v.w * v.w;
    }
    #pragma unroll
    for (int off = 32; off; off >>= 1) {
        s  += __shfl_down(s, off);
        s2 += __shfl_down(s2, off);
    }
    __shared__ float red[8];
    int wid = threadIdx.x >> 6, lane = threadIdx.x & 63;
    if (lane == 0) { red[wid * 2] = s; red[wid * 2 + 1] = s2; }
    __syncthreads();
    if (threadIdx.x == 0) {
        for (int w = 1; w < 4; ++w) { s += red[w * 2]; s2 += red[w * 2 + 1]; }
        part[(size_t)(b * nblk + blk) * 2]     = s;
        part[(size_t)(b * nblk + blk) * 2 + 1] = s2;
    }
}
__global__ __launch_bounds__(256) void gn_all(const float* __restrict__ xm,
                                              const float* __restrict__ xr,
                                              float* __restrict__ part_m,
                                              float* __restrict__ part_r) {
    if (blockIdx.x < 512) gn_body(xm, NM_, NBM, part_m, blockIdx.x);
    else                  gn_body(xr, NR_, NBR, part_r, blockIdx.x - 512);
}

// ---------------------------------------------------------------------------
// Kernel 2 (merged): block 128 = GN finalize -> per (b,c) affine;
// blocks 0..127 = fp32->bf16 conversion of the four weight matrices.
// ---------------------------------------------------------------------------
__global__ __launch_bounds__(256) void fin_w2bf(const float* __restrict__ part_m,
                                                const float* __restrict__ part_r,
                                                const float* __restrict__ gamma,
                                                const float* __restrict__ beta,
                                                float* __restrict__ am, float* __restrict__ dm,
                                                float* __restrict__ ar, float* __restrict__ dr,
                                                const float* __restrict__ W0,
                                                const float* __restrict__ W1,
                                                const float* __restrict__ W2,
                                                const float* __restrict__ W3,
                                                u16* __restrict__ dst) {
    if (blockIdx.x == 128) {
        int c = threadIdx.x;
        float g = gamma[c], be = beta[c];
        for (int b = 0; b < B_; ++b) {
            float s = 0.f, s2 = 0.f;
            for (int i = 0; i < NBM; ++i) { s += part_m[(b * NBM + i) * 2]; s2 += part_m[(b * NBM + i) * 2 + 1]; }
            float mu   = s / (float)NM_;
            float var  = s2 / (float)NM_ - mu * mu;
            float rstd = rsqrtf(var + EPS_);
            am[b * C_ + c] = rstd * g;
            dm[b * C_ + c] = be - mu * rstd * g;

            s = 0.f; s2 = 0.f;
            for (int i = 0; i < NBR; ++i) { s += part_r[(b * NBR + i) * 2]; s2 += part_r[(b * NBR + i) * 2 + 1]; }
            mu   = s / (float)NR_;
            var  = s2 / (float)NR_ - mu * mu;
            rstd = rsqrtf(var + EPS_);
            ar[b * C_ + c] = rstd * g;
            dr[b * C_ + c] = be - mu * rstd * g;
        }
        return;
    }
    int idx = blockIdx.x * 256 + threadIdx.x;   // 32768 threads, 8 elems each
    int m = idx >> 13, off = (idx & 8191) * 8;
    const float* s = (m == 0 ? W0 : m == 1 ? W1 : m == 2 ? W2 : W3) + off;
    float4 a = *(const float4*)s, b = *(const float4*)(s + 4);
    ushort4 lo; lo.x = f2bf(a.x); lo.y = f2bf(a.y); lo.z = f2bf(a.z); lo.w = f2bf(a.w);
    ushort4 hi; hi.x = f2bf(b.x); hi.y = f2bf(b.y); hi.z = f2bf(b.z); hi.w = f2bf(b.w);
    *(ushort4*)(dst + m * 65536 + off)     = lo;
    *(ushort4*)(dst + m * 65536 + off + 4) = hi;
}

// ---------------------------------------------------------------------------
// Kernel 3 (merged): normalize fp32 [b][c][P] -> bf16 transposed [b][P][256]
// for motion (blocks 0..511) and ref (512..575). LDS transpose.
// ---------------------------------------------------------------------------
__device__ void norm_body(const float* __restrict__ X,
                          const float* __restrict__ alpha,
                          const float* __restrict__ delta,
                          u16* __restrict__ Y, int P, int px, int b,
                          u16* S) {
    int p0 = px * 64;
    int tid = threadIdx.x;
    #pragma unroll
    for (int pass = 0; pass < 4; ++pass) {
        int qi = pass * 256 + tid;
        int cq = qi & 63, pq = qi >> 6;
        float4 v[4];
        #pragma unroll
        for (int j = 0; j < 4; ++j) {
            int c = cq * 4 + j;
            v[j] = *(const float4*)(X + ((size_t)b * C_ + c) * P + p0 + pq * 4);
            float a = alpha[b * C_ + c], d = delta[b * C_ + c];
            v[j].x = v[j].x * a + d; v[j].y = v[j].y * a + d;
            v[j].z = v[j].z * a + d; v[j].w = v[j].w * a + d;
        }
        #pragma unroll
        for (int jj = 0; jj < 4; ++jj) {
            ushort4 o;
            o.x = f2bf(((const float*)&v[0])[jj]);
            o.y = f2bf(((const float*)&v[1])[jj]);
            o.z = f2bf(((const float*)&v[2])[jj]);
            o.w = f2bf(((const float*)&v[3])[jj]);
            *(ushort4*)&S[(pq * 4 + jj) * 256 + cq * 4] = o;
        }
    }
    __syncthreads();
    const char* Sb = (const char*)S;
    #pragma unroll
    for (int pass = 0; pass < 8; ++pass) {
        int i = pass * 256 + tid;
        int p = i >> 5, s = i & 31;
        uint4 d = *(const uint4*)(Sb + p * 512 + s * 16);
        *(uint4*)((char*)(Y + ((size_t)b * P + p0 + p) * C_) + s * 16) = d;
    }
}
__global__ __launch_bounds__(256) void norm_all(const float* __restrict__ xm,
                                                const float* __restrict__ xr,
                                                const float* __restrict__ am,
                                                const float* __restrict__ dm,
                                                const float* __restrict__ ar,
                                                const float* __restrict__ dr,
                                                u16* __restrict__ xnm,
                                                u16* __restrict__ xnr) {
    __shared__ __align__(16) u16 S[64 * 256];
    int bid = blockIdx.x;
    if (bid < 512) norm_body(xm, am, dm, xnm, PM_, bid & 127, bid >> 7, S);
    else { int i = bid - 512; norm_body(xr, ar, dr, xnr, PR_, i & 15, i >> 4, S); }
}

// ---------------------------------------------------------------------------
// 1x1 conv body v2: X-tile staged ONCE, all 4 o-tiles (full 256 outputs)
// computed per block (W re-staged per oy; W is small and L2-hot).
// X [b][P][256] bf16, W [256o][256c] bf16. Tile 64p x (4 x 64o), K=256.
// OUT=0: u16 [b][p][o] (*oscale) | OUT=1: u16 [b][o][p] | OUT=2: f32 [b][o][p]+resid
// ---------------------------------------------------------------------------
template<int OUT>
__device__ void convB_body(char* lds,
                           const u16* __restrict__ Xb, const u16* __restrict__ Wb,
                           const float* __restrict__ bias, const float* __restrict__ resid,
                           void* __restrict__ Yv, int P, float oscale,
                           int px, int b) {
    int p0 = px * 64;
    int tid = threadIdx.x;
    int w = tid >> 6, l = tid & 63, lg = l >> 4, ln = l & 15;
    int wm = w >> 1, wn = w & 1;
    const char* Xg = (const char*)(Xb + ((size_t)b * P + p0) * C_);   // contiguous 32 KB
    #pragma unroll
    for (int i = 0; i < 8; ++i) {
        int ci = i * 4 + w;
        int d = ci * 1024 + l * 16;
        int srco = (d & ~511) | ((d & 511) ^ (((d >> 9) & 7) << 4));
        gl16(Xg + srco, lds + ci * 1024);
    }

    f32x4 acc[4][2][2];
    #pragma unroll
    for (int oy = 0; oy < 4; ++oy)
        #pragma unroll
        for (int mm = 0; mm < 2; ++mm)
            #pragma unroll
            for (int nn = 0; nn < 2; ++nn) acc[oy][mm][nn] = (f32x4)0.f;

    #pragma unroll
    for (int oy = 0; oy < 4; ++oy) {
        const char* Wg = (const char*)(Wb + (size_t)(oy * 64) * C_);  // contiguous 32 KB
        #pragma unroll
        for (int i = 0; i < 8; ++i) {
            int ci = i * 4 + w;
            int d = ci * 1024 + l * 16;
            int srco = (d & ~511) | ((d & 511) ^ (((d >> 9) & 7) << 4));
            gl16(Wg + srco, lds + 32768 + ci * 1024);
        }
        asm volatile("s_waitcnt vmcnt(0)" ::: "memory");
        __syncthreads();
        #pragma unroll
        for (int f = 0; f < 8; ++f) {
            short8 xf[2], wf[2];
            #pragma unroll
            for (int nn = 0; nn < 2; ++nn) {
                int p = wn * 32 + nn * 16 + ln;
                xf[nn] = lds8(lds + p * 512 + ((f * 64 + lg * 16) ^ ((p & 7) << 4)));
            }
            #pragma unroll
            for (int mm = 0; mm < 2; ++mm) {
                int o = wm * 32 + mm * 16 + ln;
                wf[mm] = lds8(lds + 32768 + o * 512 + ((f * 64 + lg * 16) ^ ((o & 7) << 4)));
            }
            #pragma unroll
            for (int mm = 0; mm < 2; ++mm)
                #pragma unroll
                for (int nn = 0; nn < 2; ++nn) {
                    if (OUT == 1) acc[oy][mm][nn] = mfma16(xf[nn], wf[mm], acc[oy][mm][nn]); // D[m=p][n=o]
                    else          acc[oy][mm][nn] = mfma16(wf[mm], xf[nn], acc[oy][mm][nn]); // D[m=o][n=p]
                }
        }
        __syncthreads();   // protect W region before next oy restage
    }

    // epilogues per oy (X/W regions dead; lds[0..) reused for output staging)
    #pragma unroll
    for (int oy = 0; oy < 4; ++oy) {
        int o0 = oy * 64;
        if constexpr (OUT == 0) {
            #pragma unroll
            for (int mm = 0; mm < 2; ++mm) {
                int obase = o0 + wm * 32 + mm * 16 + lg * 4;
                float b0 = bias[obase], b1 = bias[obase + 1], b2 = bias[obase + 2], b3 = bias[obase + 3];
                #pragma unroll
                for (int nn = 0; nn < 2; ++nn) {
                    int pl = wn * 32 + nn * 16 + ln;
                    int a = pl * 128 + ((wm * 64 + mm * 32 + lg * 8) ^ ((pl & 7) << 4));
                    *(u32*)(lds + a)     = pk2bf((acc[oy][mm][nn][0] + b0) * oscale, (acc[oy][mm][nn][1] + b1) * oscale);
                    *(u32*)(lds + a + 4) = pk2bf((acc[oy][mm][nn][2] + b2) * oscale, (acc[oy][mm][nn][3] + b3) * oscale);
                }
            }
            __syncthreads();
            u16* Y = (u16*)Yv;
            #pragma unroll
            for (int pass = 0; pass < 2; ++pass) {
                int i = pass * 256 + tid;
                int pl = i >> 3, s = i & 7;
                uint4 d = *(const uint4*)(lds + pl * 128 + ((s * 16) ^ ((pl & 7) << 4)));
                *(uint4*)(Y + (size_t)(b * P + p0 + pl) * C_ + o0 + s * 8) = d;
            }
            __syncthreads();
        } else if constexpr (OUT == 1) {
            #pragma unroll
            for (int mm = 0; mm < 2; ++mm) {
                int ol = wm * 32 + mm * 16 + ln;
                float bo = bias[o0 + ol];
                #pragma unroll
                for (int nn = 0; nn < 2; ++nn) {
                    int a = ol * 128 + ((wn * 64 + nn * 32 + lg * 8) ^ ((ol & 7) << 4));
                    *(u32*)(lds + a)     = pk2bf(acc[oy][mm][nn][0] + bo, acc[oy][mm][nn][1] + bo);
                    *(u32*)(lds + a + 4) = pk2bf(acc[oy][mm][nn][2] + bo, acc[oy][mm][nn][3] + bo);
                }
            }
            __syncthreads();
            u16* Y = (u16*)Yv;
            #pragma unroll
            for (int pass = 0; pass < 2; ++pass) {
                int i = pass * 256 + tid;
                int ol = i >> 3, s = i & 7;
                uint4 d = *(const uint4*)(lds + ol * 128 + ((s * 16) ^ ((ol & 7) << 4)));
                *(uint4*)(Y + (size_t)(b * C_ + o0 + ol) * P + p0 + s * 8) = d;
            }
            __syncthreads();
        } else {
            #pragma unroll
            for (int mm = 0; mm < 2; ++mm) {
                int obase = wm * 32 + mm * 16 + lg * 4;
                #pragma unroll
                for (int r = 0; r < 4; ++r) {
                    int ol = obase + r;
                    float bo = bias[o0 + ol];
                    #pragma unroll
                    for (int nn = 0; nn < 2; ++nn) {
                        int a = ol * 256 + ((wn * 128 + nn * 64 + ln * 4) ^ ((ol & 7) << 4));
                        *(float*)(lds + a) = acc[oy][mm][nn][r] + bo;
                    }
                }
            }
            __syncthreads();
            float* Y = (float*)Yv;
            #pragma unroll
            for (int pass = 0; pass < 4; ++pass) {
                int i = pass * 256 + tid;
                int ol = i >> 4, s = i & 15;
                f32x4 dv = *(const f32x4*)(lds + ol * 256 + ((s * 16) ^ ((ol & 7) << 4)));
                size_t go = (size_t)(b * C_ + o0 + ol) * P + p0 + s * 4;
                float4 rv = *(const float4*)(resid + go);
                float4 o4;
                o4.x = dv[0] + rv.x; o4.y = dv[1] + rv.y; o4.z = dv[2] + rv.z; o4.w = dv[3] + rv.w;
                *(float4*)(Y + go) = o4;
            }
            __syncthreads();
        }
    }
}

// Kernel 4 (merged): q (blocks 0..511), k (512..575), v (576..639)
__global__ __launch_bounds__(256) void convQKV(const u16* __restrict__ xnm,
                                               const u16* __restrict__ xnr,
                                               const u16* __restrict__ wall,
                                               const float* __restrict__ bq,
                                               const float* __restrict__ bk,
                                               const float* __restrict__ bv,
                                               u16* __restrict__ qT,
                                               u16* __restrict__ kT,
                                               u16* __restrict__ vh) {
    __shared__ __align__(16) char lds[65536];
    int bid = blockIdx.x;
    if (bid < 512) {
        convB_body<0>(lds, xnm, wall, bq, nullptr, qT, PM_, QSCALE, bid & 127, bid >> 7);
    } else if (bid < 576) {
        int i = bid - 512;
        convB_body<0>(lds, xnr, wall + 65536, bk, nullptr, kT, PR_, 1.f, i & 15, i >> 4);
    } else {
        int i = bid - 576;
        convB_body<1>(lds, xnr, wall + 131072, bv, nullptr, vh, PR_, 1.f, i & 15, i >> 4);
    }
}

// Kernel 6: final conv, bf16 [b][p][c] in -> fp32 [b][c][p] + residual
__global__ __launch_bounds__(256) void convO(const u16* __restrict__ aoh,
                                             const u16* __restrict__ wall,
                                             const float* __restrict__ bo,
                                             const float* __restrict__ resid,
                                             float* __restrict__ out) {
    __shared__ __align__(16) char lds[65536];
    convB_body<2>(lds, aoh, wall + 196608, bo, resid, out, PM_, 1.f,
                  blockIdx.x, blockIdx.z);
}

// ---------------------------------------------------------------------------
// Kernel 5: flash cross-attention (R7/R10-proven attn4 + compiler fence on
// the P store->load round-trip). Block = (b,t,128q), 4 waves x 32 q,
// KVBLK=64, grid 256 (1 block/CU). The P publish/reload is the ONLY LDS
// store->load pair not separated by a barrier; its ordering previously
// relied on compiler alias analysis of XOR'd char* addresses (R9/R12 NaN
// suspect). asm ""::: "memory" pins compiler order at zero cost (same-wave
// DS ops are program-ordered in HW).
// ---------------------------------------------------------------------------
__global__ __launch_bounds__(256, 1) void attn4(const u16* __restrict__ qT,  // [b][8192][256]
                                                const u16* __restrict__ kT,  // [b][1024][256]
                                                const u16* __restrict__ vh,  // [b][256][1024]
                                                u16* __restrict__ ao) {      // [b][8192][256]
    __shared__ __align__(16) char lds[147456]; // K dbuf 2x32K @0, V dbuf 2x32K @65536, P 4x4K @131072
    int b = blockIdx.z, t = blockIdx.y, q0 = blockIdx.x * 128;
    int tid = threadIdx.x, w = tid >> 6, l = tid & 63;
    int m31 = l & 31, hi = l >> 5;

    const char* Kb = (const char*)(kT + (size_t)b * PR_ * C_);
    const char* Vb = (const char*)(vh + (size_t)b * C_ * PR_);

    auto stage = [&](int buf, int kt) {
        char* Kl = lds + buf * 32768;
        char* Vl = lds + 65536 + buf * 32768;
        #pragma unroll
        for (int i = 0; i < 8; ++i) {            // K tile: contiguous 32KB, rows 512B
            int ci = i * 4 + w;
            int d = ci * 1024 + l * 16;
            int srco = (d & ~511) | ((d & 511) ^ (((d >> 9) & 7) << 4));
            gl16(Kb + (size_t)kt * 32768 + srco, Kl + ci * 1024);
        }
        #pragma unroll
        for (int i = 0; i < 8; ++i) {            // V tile: [256c][64k], rows 128B
            int ci = i * 4 + w;
            int d = ci * 1024 + l * 16;
            int c = d >> 7, s = (d >> 4) & 7;
            int srco = c * 2048 + kt * 128 + ((s * 16) ^ ((c & 7) << 4));
            gl16(Vb + srco, Vl + ci * 1024);
        }
    };

    stage(0, 0);                                 // issue first staging ASAP (async)

    // Q fragments (B operand), resident: lane holds Q[q=m31][c = ch*16 + 8*hi + e]
    const char* Qrow = (const char*)(qT + ((size_t)b * PM_ + t * HW_ + q0 + w * 32 + m31) * C_);
    short8 qf[16];
    #pragma unroll
    for (int ch = 0; ch < 16; ++ch)
        qf[ch] = __builtin_bit_cast(short8, *(const uint4*)(Qrow + ch * 32 + hi * 16));

    f32x16 acc[8];
    #pragma unroll
    for (int cb = 0; cb < 8; ++cb) acc[cb] = (f32x16)0.f;
    float m_r = -1e30f, l_r = 0.f;

    asm volatile("s_waitcnt vmcnt(0)" ::: "memory");
    __syncthreads();

    char* Pw = lds + 131072 + w * 4096;          // per-wave P [32q][128B], swz (q&7)<<4
    int swzp = (m31 & 7) << 4;

    for (int kt = 0; kt < 16; ++kt) {
        int buf = kt & 1;
        if (kt < 15) stage(buf ^ 1, kt + 1);     // async prefetch overlaps compute
        const char* Kl = lds + buf * 32768;
        const char* Vl = lds + 65536 + buf * 32768;

        // ---- S^T = K · Q : rows k (0..63), cols q = m31 ----
        f32x16 s0 = (f32x16)0.f, s1 = (f32x16)0.f;
        #pragma unroll
        for (int ch = 0; ch < 16; ++ch) {
            int off = (ch * 32 + hi * 16) ^ swzp;
            short8 k0f = lds8(Kl + m31 * 512 + off);
            short8 k1f = lds8(Kl + (32 + m31) * 512 + off);
            s0 = mfma32(k0f, qf[ch], s0);
            s1 = mfma32(k1f, qf[ch], s1);
        }

        // ---- online softmax (defer-max THR=8; exp2) ----
        float tm = -1e30f;
        #pragma unroll
        for (int e = 0; e < 16; ++e) tm = fmaxf(tm, fmaxf(s0[e], s1[e]));
        if (__any(tm > m_r + 8.f)) {             // fires on tile 0, then rarely
            float tmax = fmaxf(tm, __shfl_xor(tm, 32));
            float mn = fmaxf(m_r, tmax);
            float sc = __builtin_amdgcn_exp2f(m_r - mn);
            l_r *= sc;
            #pragma unroll
            for (int cb = 0; cb < 8; ++cb)
                #pragma unroll
                for (int e = 0; e < 16; ++e) acc[cb][e] *= sc;
            m_r = mn;
        }
        float p0[16], p1[16], rs = 0.f;
        #pragma unroll
        for (int e = 0; e < 16; ++e) { p0[e] = __builtin_amdgcn_exp2f(s0[e] - m_r); rs += p0[e]; }
        #pragma unroll
        for (int e = 0; e < 16; ++e) { p1[e] = __builtin_amdgcn_exp2f(s1[e] - m_r); rs += p1[e]; }
        l_r += rs;                                // per-lane partial; reduced once at end

        // ---- publish P: row q=m31, key0 = 8a + 4hi, e-block = 4*(a&3) ----
        #pragma unroll
        for (int a = 0; a < 8; ++a) {
            const float* parr = (a < 4) ? p0 : p1;
            int eb = (a & 3) * 4;
            uint2 d;
            d.x = pk2bf(parr[eb + 0], parr[eb + 1]);
            d.y = pk2bf(parr[eb + 2], parr[eb + 3]);
            *(uint2*)(Pw + m31 * 128 + ((a * 16 + hi * 8) ^ swzp)) = d;
        }

        // Compiler fence: forbid hoisting the bP loads above the P stores
        // (ordering otherwise rests on fragile alias analysis of XOR'd addrs).
        asm volatile("" ::: "memory");

        // ---- PV B-fragments: one b128 per 16-key chunk from own q-row ----
        short8 bP[4];
        #pragma unroll
        for (int kc = 0; kc < 4; ++kc)
            bP[kc] = lds8(Pw + m31 * 128 + ((kc * 32 + hi * 16) ^ swzp));

        // ---- O^T += V^T · P : rows c, cols q = m31 ----
        #pragma unroll
        for (int cb = 0; cb < 8; ++cb) {
            int c = cb * 32 + m31;
            int rowb = c * 128, swzc = (c & 7) << 4;
            #pragma unroll
            for (int kc = 0; kc < 4; ++kc) {
                short8 vf = lds8(Vl + rowb + ((kc * 32 + hi * 16) ^ swzc));
                acc[cb] = mfma32(vf, bP[kc], acc[cb]);
            }
        }

        asm volatile("s_waitcnt vmcnt(0)" ::: "memory");
        __syncthreads();
    }

    // ---- epilogue: reduce l across k-halves, normalize, stage [128q][256c] ----
    l_r += __shfl_xor(l_r, 32);
    float invl = 1.f / l_r;
    char* Os = lds;                               // 64 KB staging (post-barrier reuse)
    int q = w * 32 + m31;
    int swzq = (q & 7) << 4;
    #pragma unroll
    for (int cb = 0; cb < 8; ++cb)
        #pragma unroll
        for (int m = 0; m < 4; ++m) {
            uint2 d;
            d.x = pk2bf(acc[cb][4 * m + 0] * invl, acc[cb][4 * m + 1] * invl);
            d.y = pk2bf(acc[cb][4 * m + 2] * invl, acc[cb][4 * m + 3] * invl);
            *(uint2*)(Os + q * 512 + ((cb * 64 + m * 16 + hi * 8) ^ swzq)) = d;
        }
    __syncthreads();
    u16* aob = ao + ((size_t)b * PM_ + t * HW_ + q0) * C_;
    // 128 q rows x 512 B = 64 KB -> 16 passes
    #pragma unroll
    for (int pass = 0; pass < 16; ++pass) {
        int i = pass * 256 + tid;
        int qr = i >> 5, s = i & 31;
        uint4 d = *(const uint4*)(Os + qr * 512 + ((s * 16) ^ ((qr & 7) << 4)));
        *(uint4*)((char*)(aob + (size_t)qr * C_) + s * 16) = d;
    }
}

// ---------------------------------------------------------------------------
// Launcher. ws bytes:
//   0 part_m | 4096 part_r | 8192 am | 12288 dm | 16384 ar | 20480 dr
//   32768   Wbf 4x128KB (q,k,v,o)
//   1 MB    xnm bf16 [4][8192][256] (16 MB)  -- ALIASED with ao
//   17 MB   xnr (2 MB) | 19 MB qT (16 MB) | 35 MB kT (2 MB) | 37 MB vh (2 MB)
// ---------------------------------------------------------------------------
extern "C" void kernel_launch(void* const* d_in, const int* in_sizes, int n_in,
                              void* d_out, int out_size, void* d_ws, size_t ws_size,
                              hipStream_t stream) {
    const float* x_motion = (const float*)d_in[0];
    const float* x_ref    = (const float*)d_in[1];
    const float* gamma    = (const float*)d_in[2];
    const float* beta     = (const float*)d_in[3];
    const float* Wq = (const float*)d_in[4];
    const float* bq = (const float*)d_in[5];
    const float* Wk = (const float*)d_in[6];
    const float* bk = (const float*)d_in[7];
    const float* Wv = (const float*)d_in[8];
    const float* bv = (const float*)d_in[9];
    const float* Wo = (const float*)d_in[10];
    const float* bo = (const float*)d_in[11];
    float* out = (float*)d_out;
    char* base = (char*)d_ws;

    float* part_m = (float*)(base);
    float* part_r = (float*)(base + 4096);
    float* am = (float*)(base + 8192);
    float* dm = (float*)(base + 12288);
    float* ar = (float*)(base + 16384);
    float* dr = (float*)(base + 20480);
    u16* wall = (u16*)(base + 32768);
    u16* xnm = (u16*)(base + 1048576);                             // 16 MB
    u16* aoh = xnm;                                                // alias (xnm dead after convQKV)
    u16* xnr = (u16*)(base + 1048576 + 16777216);                  // 2 MB
    u16* qT  = (u16*)(base + 1048576 + 16777216 + 2097152);        // 16 MB
    u16* kTp = (u16*)(base + 1048576 + 2 * 16777216 + 2097152);    // 2 MB
    u16* vh  = (u16*)(base + 1048576 + 2 * 16777216 + 2 * 2097152);// 2 MB

    gn_all<<<dim3(576), 256, 0, stream>>>(x_motion, x_ref, part_m, part_r);
    fin_w2bf<<<dim3(129), 256, 0, stream>>>(part_m, part_r, gamma, beta,
                                            am, dm, ar, dr, Wq, Wk, Wv, Wo, wall);
    norm_all<<<dim3(576), 256, 0, stream>>>(x_motion, x_ref, am, dm, ar, dr, xnm, xnr);
    convQKV<<<dim3(640), 256, 0, stream>>>(xnm, xnr, wall, bq, bk, bv, qT, kTp, vh);
    attn4<<<dim3(8, T_, B_), 256, 0, stream>>>(qT, kTp, vh, aoh);
    convO<<<dim3(128, 1, B_), 256, 0, stream>>>(aoh, wall, bo, x_motion, out);
}